// Round 1
// baseline (410.336 us; speedup 1.0000x reference)
//
#include <hip/hip_runtime.h>
#include <cstdint>

// Problem: M=16384, K=2048, N=2048 fp8(e4m3) delayed-scaling dense fwd.
#define M_DIM 16384
#define K_DIM 2048
#define N_DIM 2048

typedef float f32x4 __attribute__((ext_vector_type(4)));

// ---------------------------------------------------------------------------
// Kernel 1: quantize x [M,K] f32 -> fp8 e4m3 (RNE via v_cvt_pk_fp8_f32),
// fused amax reduction. Each thread: 16 elements (4x float4 -> 1x uint4).
// ---------------------------------------------------------------------------
__global__ __launch_bounds__(256) void quant_x_kernel(
    const float4* __restrict__ x, uint4* __restrict__ xq,
    const float* __restrict__ scale, unsigned int* __restrict__ amax)
{
    const int gid = blockIdx.x * 256 + threadIdx.x;
    const float s = scale[0];
    float m = 0.0f;
    unsigned int pk[4];
#pragma unroll
    for (int j = 0; j < 4; ++j) {
        float4 v = x[(size_t)gid * 4 + j];
        m = fmaxf(m, fmaxf(fmaxf(fabsf(v.x), fabsf(v.y)),
                           fmaxf(fabsf(v.z), fabsf(v.w))));
        unsigned int p = __builtin_amdgcn_cvt_pk_fp8_f32(v.x * s, v.y * s, 0, false);
        pk[j] = __builtin_amdgcn_cvt_pk_fp8_f32(v.z * s, v.w * s, p, true);
    }
    xq[gid] = make_uint4(pk[0], pk[1], pk[2], pk[3]);

    // reduce amax: wave shuffle -> LDS -> one atomic per block
#pragma unroll
    for (int off = 32; off > 0; off >>= 1)
        m = fmaxf(m, __shfl_down(m, off, 64));
    __shared__ float red[4];
    if ((threadIdx.x & 63) == 0) red[threadIdx.x >> 6] = m;
    __syncthreads();
    if (threadIdx.x == 0) {
        m = fmaxf(fmaxf(red[0], red[1]), fmaxf(red[2], red[3]));
        atomicMax(amax, __float_as_uint(m));  // all values >= 0: uint order == float order
    }
}

// ---------------------------------------------------------------------------
// Kernel 2: quantize + transpose kernel [K,N] f32 -> wq [N,K] fp8, fused amax.
// 64x64 tile through LDS (stride 68 floats keeps float4 writes 16B-aligned).
// ---------------------------------------------------------------------------
__global__ __launch_bounds__(256) void quant_w_kernel(
    const float* __restrict__ w, uint8_t* __restrict__ wq,
    const float* __restrict__ scale, unsigned int* __restrict__ amax)
{
    __shared__ float tile[64][68];
    const int t = threadIdx.x;
    const int nb = blockIdx.x * 64;
    const int kb = blockIdx.y * 64;
    const float s = scale[1];
    float m = 0.0f;
#pragma unroll
    for (int j = 0; j < 4; ++j) {
        int f = j * 256 + t;           // float4 index within 64x64 tile
        int row = f >> 4;              // k within tile
        int c4 = f & 15;               // float4 column
        float4 v = *(const float4*)(w + (size_t)(kb + row) * N_DIM + nb + c4 * 4);
        m = fmaxf(m, fmaxf(fmaxf(fabsf(v.x), fabsf(v.y)),
                           fmaxf(fabsf(v.z), fabsf(v.w))));
        *(float4*)(&tile[row][c4 * 4]) = v;
    }
    __syncthreads();
    const int n = t >> 2, c = t & 3;   // output row n (64), 16B chunk c (4)
    unsigned int pk[4];
#pragma unroll
    for (int jj = 0; jj < 4; ++jj) {
        float f0 = tile[c * 16 + jj * 4 + 0][n] * s;
        float f1 = tile[c * 16 + jj * 4 + 1][n] * s;
        float f2 = tile[c * 16 + jj * 4 + 2][n] * s;
        float f3 = tile[c * 16 + jj * 4 + 3][n] * s;
        unsigned int p = __builtin_amdgcn_cvt_pk_fp8_f32(f0, f1, 0, false);
        pk[jj] = __builtin_amdgcn_cvt_pk_fp8_f32(f2, f3, p, true);
    }
    *(uint4*)(wq + (size_t)(nb + n) * K_DIM + kb + c * 16) = make_uint4(pk[0], pk[1], pk[2], pk[3]);

#pragma unroll
    for (int off = 32; off > 0; off >>= 1)
        m = fmaxf(m, __shfl_down(m, off, 64));
    __shared__ float red[4];
    if ((t & 63) == 0) red[t >> 6] = m;
    __syncthreads();
    if (t == 0) {
        m = fmaxf(fmaxf(red[0], red[1]), fmaxf(red[2], red[3]));
        atomicMax(amax, __float_as_uint(m));
    }
}

// ---------------------------------------------------------------------------
// Kernel 3: fp8 GEMM.  C[m,n] = sum_k Aq[m,k]*Bq[n,k]  (Bq is w^T, [N,K]).
// 128x128 tile, BK=128 (16KB A + 16KB B in LDS), global_load_lds width=16,
// XOR-8 chunk swizzle (LDS dest must stay lane-linear; swizzle applied to the
// per-lane GLOBAL address instead), mfma_f32_16x16x32_fp8_fp8, 2x2 waves each
// computing 64x64 via 4x4 accumulator tiles.
// ---------------------------------------------------------------------------
__global__ __launch_bounds__(256) void gemm_fp8_kernel(
    const uint8_t* __restrict__ Aq, const uint8_t* __restrict__ Bq,
    const float* __restrict__ scale, float* __restrict__ C)
{
    __shared__ uint8_t lA[128 * 128];
    __shared__ uint8_t lB[128 * 128];
    const int tid  = threadIdx.x;
    const int wave = tid >> 6;
    const int lane = tid & 63;
    const int wm = wave >> 1, wn = wave & 1;   // 2x2 wave grid
    const int q = lane >> 4, r = lane & 15;

    const int bn = blockIdx.x;                 // 0..15
    const int bm = blockIdx.y;                 // 0..127
    const size_t a_base = (size_t)bm * 128 * K_DIM;
    const size_t b_base = (size_t)bn * 128 * K_DIM;

    // staging geometry (c = LDS 16B-chunk index; global chunk = slot ^ (row&7))
    const int c0   = wave * 64 + lane;         // chunk for j-th issue: c0 + j*256
    f32x4 acc[4][4];
#pragma unroll
    for (int i = 0; i < 4; ++i)
#pragma unroll
        for (int j = 0; j < 4; ++j) acc[i][j] = (f32x4){0.f, 0.f, 0.f, 0.f};

    for (int kt = 0; kt < K_DIM / 128; ++kt) {
        __syncthreads();
        const size_t kg = (size_t)kt * 128;
#pragma unroll
        for (int j = 0; j < 4; ++j) {
            const int c   = j * 256 + c0;
            const int row = c >> 3;
            const int gch = (c & 7) ^ (row & 7);
            const uint8_t* ga = Aq + a_base + (size_t)row * K_DIM + kg + gch * 16;
            const uint8_t* gb = Bq + b_base + (size_t)row * K_DIM + kg + gch * 16;
            __builtin_amdgcn_global_load_lds(
                (const __attribute__((address_space(1))) uint32_t*)ga,
                (__attribute__((address_space(3))) uint32_t*)(lA + (size_t)(j * 256 + wave * 64) * 16),
                16, 0, 0);
            __builtin_amdgcn_global_load_lds(
                (const __attribute__((address_space(1))) uint32_t*)gb,
                (__attribute__((address_space(3))) uint32_t*)(lB + (size_t)(j * 256 + wave * 64) * 16),
                16, 0, 0);
        }
        __syncthreads();
#pragma unroll
        for (int ko = 0; ko < 4; ++ko) {
            long long a_frag[4], b_frag[4];
            const int chunk = ko * 2 + (q >> 1);
            const int sub   = (q & 1) * 8;
#pragma unroll
            for (int mi = 0; mi < 4; ++mi) {
                const int ra = wm * 64 + mi * 16 + r;
                a_frag[mi] = *(const long long*)(lA + ra * 128 + ((chunk ^ (ra & 7)) << 4) + sub);
                const int rb = wn * 64 + mi * 16 + r;
                b_frag[mi] = *(const long long*)(lB + rb * 128 + ((chunk ^ (rb & 7)) << 4) + sub);
            }
#pragma unroll
            for (int mi = 0; mi < 4; ++mi)
#pragma unroll
                for (int ni = 0; ni < 4; ++ni)
                    acc[mi][ni] = __builtin_amdgcn_mfma_f32_16x16x32_fp8_fp8(
                        a_frag[mi], b_frag[ni], acc[mi][ni], 0, 0, 0);
        }
    }

    // epilogue: D col = lane&15, row = q*4 + reg (m89-verified layout)
    const float sinv = (1.0f / scale[0]) * (1.0f / scale[1]);
#pragma unroll
    for (int mi = 0; mi < 4; ++mi) {
#pragma unroll
        for (int ni = 0; ni < 4; ++ni) {
            const int col  = bn * 128 + wn * 64 + ni * 16 + r;
            const int row0 = bm * 128 + wm * 64 + mi * 16 + q * 4;
#pragma unroll
            for (int rr = 0; rr < 4; ++rr)
                C[(size_t)(row0 + rr) * N_DIM + col] = acc[mi][ni][rr] * sinv;
        }
    }
}

// ---------------------------------------------------------------------------
// Kernel 4: scale update (faithful _sf_compute incl. tf.where ordering) +
// rolled amax history (always zeros for 1-row history).
// ---------------------------------------------------------------------------
__global__ void finalize_kernel(const float* __restrict__ scale,
                                const unsigned int* __restrict__ amax_bits,
                                float* __restrict__ out_tail)
{
    const int i = threadIdx.x;
    if (i < 2) {
        const float amax = __uint_as_float(amax_bits[i]);
        const float sc = scale[i];
        const float e = floorf(log2f(448.0f / amax));
        float sf = roundf(exp2f(fabsf(e)));
        sf = (amax > 0.0f) ? sf : sc;
        sf = isinf(amax) ? sf : sc;      // faithful: finite amax collapses to scale
        if (e < 0.0f) sf = 1.0f / sf;
        out_tail[i] = sf;                // new_scale
        out_tail[2 + i] = 0.0f;          // rolled history (single row -> zeros)
    }
}

// ---------------------------------------------------------------------------
extern "C" void kernel_launch(void* const* d_in, const int* in_sizes, int n_in,
                              void* d_out, int out_size, void* d_ws, size_t ws_size,
                              hipStream_t stream)
{
    const float* x     = (const float*)d_in[0];
    const float* w     = (const float*)d_in[1];
    const float* scale = (const float*)d_in[2];
    // d_in[3] (scale_inv) and d_in[4] (amax_history) do not affect outputs.

    uint8_t* ws = (uint8_t*)d_ws;
    uint8_t* xq = ws;                                            // M*K fp8 (32 MB)
    uint8_t* wq = ws + (size_t)M_DIM * K_DIM;                    // N*K fp8 (4 MB)
    unsigned int* amax = (unsigned int*)(ws + (size_t)M_DIM * K_DIM + (size_t)N_DIM * K_DIM);

    hipMemsetAsync(amax, 0, 2 * sizeof(unsigned int), stream);   // ws is poisoned 0xAA

    quant_x_kernel<<<(M_DIM * K_DIM / 16) / 256, 256, 0, stream>>>(
        (const float4*)x, (uint4*)xq, scale, amax);

    dim3 gw(N_DIM / 64, K_DIM / 64);
    quant_w_kernel<<<gw, 256, 0, stream>>>(w, wq, scale, amax + 1);

    dim3 gg(N_DIM / 128, M_DIM / 128);
    gemm_fp8_kernel<<<gg, 256, 0, stream>>>(xq, wq, scale, (float*)d_out);

    finalize_kernel<<<1, 64, 0, stream>>>(scale, amax,
                                          (float*)d_out + (size_t)M_DIM * N_DIM);
}

// Round 2
// 349.273 us; speedup vs baseline: 1.1748x; 1.1748x over previous
//
#include <hip/hip_runtime.h>
#include <cstdint>

// Problem: M=16384, K=2048, N=2048 fp8(e4m3) delayed-scaling dense fwd.
#define M_DIM 16384
#define K_DIM 2048
#define N_DIM 2048

typedef float f32x4 __attribute__((ext_vector_type(4)));
typedef int   i32x8 __attribute__((ext_vector_type(8)));

// ---------------------------------------------------------------------------
// Kernel 1: quantize x [M,K] f32 -> fp8 e4m3 (RNE via v_cvt_pk_fp8_f32),
// fused amax. Grid-stride float4 pattern: every load/store instruction is
// 64 lanes x 16B consecutive = perfectly coalesced 1KB.
// ---------------------------------------------------------------------------
__global__ __launch_bounds__(256) void quant_x_kernel(
    const float4* __restrict__ x, uint4* __restrict__ xq,
    const float* __restrict__ scale, unsigned int* __restrict__ amax)
{
    const int gid = blockIdx.x * 256 + threadIdx.x;   // 4096*256 = 1048576 threads
    const float s = scale[0];
    float m = 0.0f;
#pragma unroll
    for (int j = 0; j < 8; ++j) {
        float4 v = x[gid + j * 1048576];
        m = fmaxf(m, fmaxf(fmaxf(fabsf(v.x), fabsf(v.y)),
                           fmaxf(fabsf(v.z), fabsf(v.w))));
        unsigned int p0 = __builtin_amdgcn_cvt_pk_fp8_f32(v.x * s, v.y * s, 0, false);
        unsigned int p  = __builtin_amdgcn_cvt_pk_fp8_f32(v.z * s, v.w * s, p0, true);
        // store one dword per float4 (4 fp8); gather into uint4 every 4 j's
        ((unsigned int*)xq)[gid + j * 1048576] = p;
    }

#pragma unroll
    for (int off = 32; off > 0; off >>= 1)
        m = fmaxf(m, __shfl_down(m, off, 64));
    __shared__ float red[4];
    if ((threadIdx.x & 63) == 0) red[threadIdx.x >> 6] = m;
    __syncthreads();
    if (threadIdx.x == 0) {
        m = fmaxf(fmaxf(red[0], red[1]), fmaxf(red[2], red[3]));
        atomicMax(amax, __float_as_uint(m));  // values >= 0: uint order == float order
    }
}

// ---------------------------------------------------------------------------
// Kernel 2: quantize + transpose kernel [K,N] f32 -> wq [N,K] fp8, fused amax.
// ---------------------------------------------------------------------------
__global__ __launch_bounds__(256) void quant_w_kernel(
    const float* __restrict__ w, uint8_t* __restrict__ wq,
    const float* __restrict__ scale, unsigned int* __restrict__ amax)
{
    __shared__ float tile[64][68];
    const int t = threadIdx.x;
    const int nb = blockIdx.x * 64;
    const int kb = blockIdx.y * 64;
    const float s = scale[1];
    float m = 0.0f;
#pragma unroll
    for (int j = 0; j < 4; ++j) {
        int f = j * 256 + t;
        int row = f >> 4;
        int c4 = f & 15;
        float4 v = *(const float4*)(w + (size_t)(kb + row) * N_DIM + nb + c4 * 4);
        m = fmaxf(m, fmaxf(fmaxf(fabsf(v.x), fabsf(v.y)),
                           fmaxf(fabsf(v.z), fabsf(v.w))));
        *(float4*)(&tile[row][c4 * 4]) = v;
    }
    __syncthreads();
    const int n = t >> 2, c = t & 3;
    unsigned int pk[4];
#pragma unroll
    for (int jj = 0; jj < 4; ++jj) {
        float f0 = tile[c * 16 + jj * 4 + 0][n] * s;
        float f1 = tile[c * 16 + jj * 4 + 1][n] * s;
        float f2 = tile[c * 16 + jj * 4 + 2][n] * s;
        float f3 = tile[c * 16 + jj * 4 + 3][n] * s;
        unsigned int p = __builtin_amdgcn_cvt_pk_fp8_f32(f0, f1, 0, false);
        pk[jj] = __builtin_amdgcn_cvt_pk_fp8_f32(f2, f3, p, true);
    }
    *(uint4*)(wq + (size_t)(nb + n) * K_DIM + kb + c * 16) = make_uint4(pk[0], pk[1], pk[2], pk[3]);

#pragma unroll
    for (int off = 32; off > 0; off >>= 1)
        m = fmaxf(m, __shfl_down(m, off, 64));
    __shared__ float red[4];
    if ((t & 63) == 0) red[t >> 6] = m;
    __syncthreads();
    if (t == 0) {
        m = fmaxf(fmaxf(red[0], red[1]), fmaxf(red[2], red[3]));
        atomicMax(amax, __float_as_uint(m));
    }
}

// ---------------------------------------------------------------------------
// Kernel 3: MX-scaled fp8 GEMM.  C[m,n] = sum_k Aq[m,k]*Bq[n,k].
// mfma_scale_f32_16x16x128_f8f6f4 with all e8m0 scales = 1.0 (0x7F) runs at
// the ~4.7 PF MX rate (2x non-scaled fp8).  BK=128 = one MFMA K per tile.
//
// LDS is stored in MFMA-FRAGMENT ORDER: for row group g=row>>4 (8 groups of
// 16 rows), lane l's fragment (row = g*16 + (l&15), k = (l>>4)*32 + 0..31)
// lives at  g*2048 + l*32.  Fragment read = 2x ds_read_b128 at lane-linear
// stride 32 -> 2-way bank aliasing (free, m136).  global_load_lds writes
// lane-linear 16B, so we invert the layout on the GLOBAL address side; each
// staging instruction still reads 16 complete 64B cache lines.
// ---------------------------------------------------------------------------
__global__ __launch_bounds__(256) void gemm_fp8_kernel(
    const uint8_t* __restrict__ Aq, const uint8_t* __restrict__ Bq,
    const float* __restrict__ scale, float* __restrict__ C)
{
    __shared__ uint8_t lA[16384];
    __shared__ uint8_t lB[16384];
    const int tid  = threadIdx.x;
    const int wave = tid >> 6;
    const int lane = tid & 63;
    const int wm = wave >> 1, wn = wave & 1;   // 2x2 wave grid, 64x64 per wave
    const int q = lane >> 4, r = lane & 15;

    const int bn = blockIdx.x;                 // 0..15
    const int bm = blockIdx.y;                 // 0..127
    const size_t a_base = (size_t)bm * 128 * K_DIM;
    const size_t b_base = (size_t)bn * 128 * K_DIM;

    // Staging geometry: 16 LDS segments of 1KB; wave handles s = j*4 + wave.
    // For segment s: g = s>>1, hh = s&1; lds dst = s*1024 + lane*16.
    // Inverse map: fl = hh*32 + (lane>>1); row = g*16 + (fl&15);
    //              koff = (fl>>4)*32 + (lane&1)*16.
    int srow[4], skoff[4], sdst[4];
#pragma unroll
    for (int j = 0; j < 4; ++j) {
        const int s  = j * 4 + wave;
        const int g  = s >> 1, hh = s & 1;
        const int fl = hh * 32 + (lane >> 1);
        srow[j]  = g * 16 + (fl & 15);
        skoff[j] = (fl >> 4) * 32 + (lane & 1) * 16;
        sdst[j]  = s * 1024 + lane * 16;
    }

    f32x4 acc[4][4];
#pragma unroll
    for (int i = 0; i < 4; ++i)
#pragma unroll
        for (int j = 0; j < 4; ++j) acc[i][j] = (f32x4){0.f, 0.f, 0.f, 0.f};

    const int SONE = 0x7F7F7F7F;   // e8m0 scale = 1.0 in every byte

    for (int kt = 0; kt < K_DIM / 128; ++kt) {
        __syncthreads();
        const size_t kg = (size_t)kt * 128;
#pragma unroll
        for (int j = 0; j < 4; ++j) {
            const uint8_t* ga = Aq + a_base + (size_t)srow[j] * K_DIM + kg + skoff[j];
            const uint8_t* gb = Bq + b_base + (size_t)srow[j] * K_DIM + kg + skoff[j];
            __builtin_amdgcn_global_load_lds(
                (const __attribute__((address_space(1))) uint32_t*)ga,
                (__attribute__((address_space(3))) uint32_t*)(lA + sdst[j]), 16, 0, 0);
            __builtin_amdgcn_global_load_lds(
                (const __attribute__((address_space(1))) uint32_t*)gb,
                (__attribute__((address_space(3))) uint32_t*)(lB + sdst[j]), 16, 0, 0);
        }
        __syncthreads();

        i32x8 a_frag[4], b_frag[4];
#pragma unroll
        for (int mi = 0; mi < 4; ++mi) {
            const uint8_t* pa = lA + (wm * 4 + mi) * 2048 + lane * 32;
            int4 lo = *(const int4*)pa;
            int4 hi = *(const int4*)(pa + 16);
            a_frag[mi] = (i32x8){lo.x, lo.y, lo.z, lo.w, hi.x, hi.y, hi.z, hi.w};
        }
#pragma unroll
        for (int ni = 0; ni < 4; ++ni) {
            const uint8_t* pb = lB + (wn * 4 + ni) * 2048 + lane * 32;
            int4 lo = *(const int4*)pb;
            int4 hi = *(const int4*)(pb + 16);
            b_frag[ni] = (i32x8){lo.x, lo.y, lo.z, lo.w, hi.x, hi.y, hi.z, hi.w};
        }
#pragma unroll
        for (int mi = 0; mi < 4; ++mi)
#pragma unroll
            for (int ni = 0; ni < 4; ++ni)
                acc[mi][ni] = __builtin_amdgcn_mfma_scale_f32_16x16x128_f8f6f4(
                    a_frag[mi], b_frag[ni], acc[mi][ni],
                    0 /*cbsz: fp8*/, 0 /*blgp: fp8*/,
                    0, SONE, 0, SONE);
    }

    // epilogue: D col = lane&15, row = q*4 + reg (m89-verified, shape-determined)
    const float sinv = (1.0f / scale[0]) * (1.0f / scale[1]);
#pragma unroll
    for (int mi = 0; mi < 4; ++mi) {
#pragma unroll
        for (int ni = 0; ni < 4; ++ni) {
            const int col  = bn * 128 + wn * 64 + ni * 16 + r;
            const int row0 = bm * 128 + wm * 64 + mi * 16 + q * 4;
#pragma unroll
            for (int rr = 0; rr < 4; ++rr)
                C[(size_t)(row0 + rr) * N_DIM + col] = acc[mi][ni][rr] * sinv;
        }
    }
}

// ---------------------------------------------------------------------------
// Kernel 4: scale update (faithful _sf_compute incl. tf.where ordering) +
// rolled amax history (always zeros for 1-row history).
// ---------------------------------------------------------------------------
__global__ void finalize_kernel(const float* __restrict__ scale,
                                const unsigned int* __restrict__ amax_bits,
                                float* __restrict__ out_tail)
{
    const int i = threadIdx.x;
    if (i < 2) {
        const float amax = __uint_as_float(amax_bits[i]);
        const float sc = scale[i];
        const float e = floorf(log2f(448.0f / amax));
        float sf = roundf(exp2f(fabsf(e)));
        sf = (amax > 0.0f) ? sf : sc;
        sf = isinf(amax) ? sf : sc;      // faithful: finite amax collapses to scale
        if (e < 0.0f) sf = 1.0f / sf;
        out_tail[i] = sf;                // new_scale
        out_tail[2 + i] = 0.0f;          // rolled history (single row -> zeros)
    }
}

// ---------------------------------------------------------------------------
extern "C" void kernel_launch(void* const* d_in, const int* in_sizes, int n_in,
                              void* d_out, int out_size, void* d_ws, size_t ws_size,
                              hipStream_t stream)
{
    const float* x     = (const float*)d_in[0];
    const float* w     = (const float*)d_in[1];
    const float* scale = (const float*)d_in[2];

    uint8_t* ws = (uint8_t*)d_ws;
    uint8_t* xq = ws;                                            // M*K fp8 (32 MB)
    uint8_t* wq = ws + (size_t)M_DIM * K_DIM;                    // N*K fp8 (4 MB)
    unsigned int* amax = (unsigned int*)(ws + (size_t)M_DIM * K_DIM + (size_t)N_DIM * K_DIM);

    hipMemsetAsync(amax, 0, 2 * sizeof(unsigned int), stream);

    quant_x_kernel<<<4096, 256, 0, stream>>>(
        (const float4*)x, (uint4*)xq, scale, amax);

    dim3 gw(N_DIM / 64, K_DIM / 64);
    quant_w_kernel<<<gw, 256, 0, stream>>>(w, wq, scale, amax + 1);

    dim3 gg(N_DIM / 128, M_DIM / 128);
    gemm_fp8_kernel<<<gg, 256, 0, stream>>>(xq, wq, scale, (float*)d_out);

    finalize_kernel<<<1, 64, 0, stream>>>(scale, amax,
                                          (float*)d_out + (size_t)M_DIM * N_DIM);
}

// Round 3
// 336.799 us; speedup vs baseline: 1.2183x; 1.0370x over previous
//
#include <hip/hip_runtime.h>
#include <cstdint>

// Problem: M=16384, K=2048, N=2048 fp8(e4m3) delayed-scaling dense fwd.
#define M_DIM 16384
#define K_DIM 2048
#define N_DIM 2048

typedef float f32x4 __attribute__((ext_vector_type(4)));
typedef int   i32x8 __attribute__((ext_vector_type(8)));

// ---------------------------------------------------------------------------
// Kernel 1: quantize x [M,K] f32 -> fp8 e4m3 (RNE via v_cvt_pk_fp8_f32),
// fused amax. Grid-stride float4 loads: 64 lanes x 16B consecutive = 1KB/instr.
// ---------------------------------------------------------------------------
__global__ __launch_bounds__(256) void quant_x_kernel(
    const float4* __restrict__ x, uint4* __restrict__ xq,
    const float* __restrict__ scale, unsigned int* __restrict__ amax)
{
    const int gid = blockIdx.x * 256 + threadIdx.x;   // 4096*256 = 1048576 threads
    const float s = scale[0];
    float m = 0.0f;
#pragma unroll
    for (int j = 0; j < 8; ++j) {
        float4 v = x[gid + j * 1048576];
        m = fmaxf(m, fmaxf(fmaxf(fabsf(v.x), fabsf(v.y)),
                           fmaxf(fabsf(v.z), fabsf(v.w))));
        unsigned int p0 = __builtin_amdgcn_cvt_pk_fp8_f32(v.x * s, v.y * s, 0, false);
        unsigned int p  = __builtin_amdgcn_cvt_pk_fp8_f32(v.z * s, v.w * s, p0, true);
        ((unsigned int*)xq)[gid + j * 1048576] = p;   // 4 fp8 per dword, coalesced
    }

#pragma unroll
    for (int off = 32; off > 0; off >>= 1)
        m = fmaxf(m, __shfl_down(m, off, 64));
    __shared__ float red[4];
    if ((threadIdx.x & 63) == 0) red[threadIdx.x >> 6] = m;
    __syncthreads();
    if (threadIdx.x == 0) {
        m = fmaxf(fmaxf(red[0], red[1]), fmaxf(red[2], red[3]));
        atomicMax(amax, __float_as_uint(m));  // values >= 0: uint order == float order
    }
}

// ---------------------------------------------------------------------------
// Kernel 2: quantize + transpose kernel [K,N] f32 -> wq [N,K] fp8, fused amax.
// ---------------------------------------------------------------------------
__global__ __launch_bounds__(256) void quant_w_kernel(
    const float* __restrict__ w, uint8_t* __restrict__ wq,
    const float* __restrict__ scale, unsigned int* __restrict__ amax)
{
    __shared__ float tile[64][68];
    const int t = threadIdx.x;
    const int nb = blockIdx.x * 64;
    const int kb = blockIdx.y * 64;
    const float s = scale[1];
    float m = 0.0f;
#pragma unroll
    for (int j = 0; j < 4; ++j) {
        int f = j * 256 + t;
        int row = f >> 4;
        int c4 = f & 15;
        float4 v = *(const float4*)(w + (size_t)(kb + row) * N_DIM + nb + c4 * 4);
        m = fmaxf(m, fmaxf(fmaxf(fabsf(v.x), fabsf(v.y)),
                           fmaxf(fabsf(v.z), fabsf(v.w))));
        *(float4*)(&tile[row][c4 * 4]) = v;
    }
    __syncthreads();
    const int n = t >> 2, c = t & 3;
    unsigned int pk[4];
#pragma unroll
    for (int jj = 0; jj < 4; ++jj) {
        float f0 = tile[c * 16 + jj * 4 + 0][n] * s;
        float f1 = tile[c * 16 + jj * 4 + 1][n] * s;
        float f2 = tile[c * 16 + jj * 4 + 2][n] * s;
        float f3 = tile[c * 16 + jj * 4 + 3][n] * s;
        unsigned int p = __builtin_amdgcn_cvt_pk_fp8_f32(f0, f1, 0, false);
        pk[jj] = __builtin_amdgcn_cvt_pk_fp8_f32(f2, f3, p, true);
    }
    *(uint4*)(wq + (size_t)(nb + n) * K_DIM + kb + c * 16) = make_uint4(pk[0], pk[1], pk[2], pk[3]);

#pragma unroll
    for (int off = 32; off > 0; off >>= 1)
        m = fmaxf(m, __shfl_down(m, off, 64));
    __shared__ float red[4];
    if ((t & 63) == 0) red[t >> 6] = m;
    __syncthreads();
    if (t == 0) {
        m = fmaxf(fmaxf(red[0], red[1]), fmaxf(red[2], red[3]));
        atomicMax(amax, __float_as_uint(m));
    }
}

// ---------------------------------------------------------------------------
// Kernel 3: MX-scaled fp8 GEMM.  C[m,n] = sum_k Aq[m,k]*Bq[n,k].
// mfma_scale_f32_16x16x128_f8f6f4, all e8m0 scales = 1.0 (0x7F).
//
// LDS layout (per matrix): 8 row-groups of 16 rows. Group g occupies
// [g*2080, g*2080+1024) = fragment half0 (k 0..15 of each lane's 32B) and
// [g*2080+1040, g*2080+2064) = half1, with a 16B pad between halves.
// Lane l's fragment: lo b128 at g*2080 + l*32 + (l>>5)*16, hi at +16.
// Bank math: dword 8l + 4*(l>>5) -> lanes 0-31 cover bank-quads
// {0-3,8-11,16-19,24-27}, lanes 32-63 cover {4-7,12-15,20-23,28-31}:
// all 32 banks x 8 lanes = 8-phase structural minimum, conflict-free.
// Staging: segment s=2g+h is contiguous 1KB at g*2080+h*1040, lane-linear
// 16B dst (global_load_lds requirement); inverse map keeps each staging
// instruction reading 16 complete 64B cache lines.
// ---------------------------------------------------------------------------
#define GSTRIDE 2080
__global__ __launch_bounds__(256) void gemm_fp8_kernel(
    const uint8_t* __restrict__ Aq, const uint8_t* __restrict__ Bq,
    const float* __restrict__ scale, float* __restrict__ C)
{
    __shared__ uint8_t lA[8 * GSTRIDE];
    __shared__ uint8_t lB[8 * GSTRIDE];
    const int tid  = threadIdx.x;
    const int wave = tid >> 6;
    const int lane = tid & 63;
    const int wm = wave >> 1, wn = wave & 1;   // 2x2 wave grid, 64x64 per wave
    const int q = lane >> 4, r = lane & 15;

    const int bn = blockIdx.x;                 // 0..15
    const int bm = blockIdx.y;                 // 0..127
    const size_t a_base = (size_t)bm * 128 * K_DIM;
    const size_t b_base = (size_t)bn * 128 * K_DIM;

    // Staging geometry: wave handles segments s = j*4 + wave, s = 2g + h.
    int srow[4], skoff[4], sdst[4];
#pragma unroll
    for (int j = 0; j < 4; ++j) {
        const int s  = j * 4 + wave;
        const int g  = s >> 1, hh = s & 1;
        const int fl = hh * 32 + (lane >> 1);
        srow[j]  = g * 16 + (fl & 15);
        skoff[j] = (fl >> 4) * 32 + (lane & 1) * 16;
        sdst[j]  = g * GSTRIDE + hh * 1040 + lane * 16;
    }
    // Fragment read base offset for this lane (within a group)
    const int frag_off = lane * 32 + (lane >> 5) * 16;

    f32x4 acc[4][4];
#pragma unroll
    for (int i = 0; i < 4; ++i)
#pragma unroll
        for (int j = 0; j < 4; ++j) acc[i][j] = (f32x4){0.f, 0.f, 0.f, 0.f};

    const int SONE = 0x7F7F7F7F;   // e8m0 scale = 1.0 in every byte

    for (int kt = 0; kt < K_DIM / 128; ++kt) {
        __syncthreads();
        const size_t kg = (size_t)kt * 128;
#pragma unroll
        for (int j = 0; j < 4; ++j) {
            const uint8_t* ga = Aq + a_base + (size_t)srow[j] * K_DIM + kg + skoff[j];
            const uint8_t* gb = Bq + b_base + (size_t)srow[j] * K_DIM + kg + skoff[j];
            __builtin_amdgcn_global_load_lds(
                (const __attribute__((address_space(1))) uint32_t*)ga,
                (__attribute__((address_space(3))) uint32_t*)(lA + sdst[j]), 16, 0, 0);
            __builtin_amdgcn_global_load_lds(
                (const __attribute__((address_space(1))) uint32_t*)gb,
                (__attribute__((address_space(3))) uint32_t*)(lB + sdst[j]), 16, 0, 0);
        }
        __syncthreads();

        i32x8 a_frag[4], b_frag[4];
#pragma unroll
        for (int mi = 0; mi < 4; ++mi) {
            const uint8_t* pa = lA + (wm * 4 + mi) * GSTRIDE + frag_off;
            int4 lo = *(const int4*)pa;
            int4 hi = *(const int4*)(pa + 16);
            a_frag[mi] = (i32x8){lo.x, lo.y, lo.z, lo.w, hi.x, hi.y, hi.z, hi.w};
        }
#pragma unroll
        for (int ni = 0; ni < 4; ++ni) {
            const uint8_t* pb = lB + (wn * 4 + ni) * GSTRIDE + frag_off;
            int4 lo = *(const int4*)pb;
            int4 hi = *(const int4*)(pb + 16);
            b_frag[ni] = (i32x8){lo.x, lo.y, lo.z, lo.w, hi.x, hi.y, hi.z, hi.w};
        }
#pragma unroll
        for (int mi = 0; mi < 4; ++mi)
#pragma unroll
            for (int ni = 0; ni < 4; ++ni)
                acc[mi][ni] = __builtin_amdgcn_mfma_scale_f32_16x16x128_f8f6f4(
                    a_frag[mi], b_frag[ni], acc[mi][ni],
                    0 /*cbsz: fp8*/, 0 /*blgp: fp8*/,
                    0, SONE, 0, SONE);
    }

    // epilogue: D col = lane&15, row = q*4 + reg (m89-verified, shape-determined)
    const float sinv = (1.0f / scale[0]) * (1.0f / scale[1]);
#pragma unroll
    for (int mi = 0; mi < 4; ++mi) {
#pragma unroll
        for (int ni = 0; ni < 4; ++ni) {
            const int col  = bn * 128 + wn * 64 + ni * 16 + r;
            const int row0 = bm * 128 + wm * 64 + mi * 16 + q * 4;
#pragma unroll
            for (int rr = 0; rr < 4; ++rr)
                C[(size_t)(row0 + rr) * N_DIM + col] = acc[mi][ni][rr] * sinv;
        }
    }
}

// ---------------------------------------------------------------------------
// Kernel 4: scale update (faithful _sf_compute incl. tf.where ordering) +
// rolled amax history (always zeros for 1-row history).
// ---------------------------------------------------------------------------
__global__ void finalize_kernel(const float* __restrict__ scale,
                                const unsigned int* __restrict__ amax_bits,
                                float* __restrict__ out_tail)
{
    const int i = threadIdx.x;
    if (i < 2) {
        const float amax = __uint_as_float(amax_bits[i]);
        const float sc = scale[i];
        const float e = floorf(log2f(448.0f / amax));
        float sf = roundf(exp2f(fabsf(e)));
        sf = (amax > 0.0f) ? sf : sc;
        sf = isinf(amax) ? sf : sc;      // faithful: finite amax collapses to scale
        if (e < 0.0f) sf = 1.0f / sf;
        out_tail[i] = sf;                // new_scale
        out_tail[2 + i] = 0.0f;          // rolled history (single row -> zeros)
    }
}

// ---------------------------------------------------------------------------
extern "C" void kernel_launch(void* const* d_in, const int* in_sizes, int n_in,
                              void* d_out, int out_size, void* d_ws, size_t ws_size,
                              hipStream_t stream)
{
    const float* x     = (const float*)d_in[0];
    const float* w     = (const float*)d_in[1];
    const float* scale = (const float*)d_in[2];

    uint8_t* ws = (uint8_t*)d_ws;
    uint8_t* xq = ws;                                            // M*K fp8 (32 MB)
    uint8_t* wq = ws + (size_t)M_DIM * K_DIM;                    // N*K fp8 (4 MB)
    unsigned int* amax = (unsigned int*)(ws + (size_t)M_DIM * K_DIM + (size_t)N_DIM * K_DIM);

    hipMemsetAsync(amax, 0, 2 * sizeof(unsigned int), stream);

    quant_x_kernel<<<4096, 256, 0, stream>>>(
        (const float4*)x, (uint4*)xq, scale, amax);

    dim3 gw(N_DIM / 64, K_DIM / 64);
    quant_w_kernel<<<gw, 256, 0, stream>>>(w, wq, scale, amax + 1);

    dim3 gg(N_DIM / 128, M_DIM / 128);
    gemm_fp8_kernel<<<gg, 256, 0, stream>>>(xq, wq, scale, (float*)d_out);

    finalize_kernel<<<1, 64, 0, stream>>>(scale, amax,
                                          (float*)d_out + (size_t)M_DIM * N_DIM);
}